// Round 5
// baseline (723.685 us; speedup 1.0000x reference)
//
#include <hip/hip_runtime.h>
#include <hip/hip_bf16.h>
#include <math.h>

#define N_NODES 50000
#define N_EDGES 600000
#define D_IN    44

// ---------------- CSR build ----------------

__global__ void k_zero(int* p, int n) {
    int i = blockIdx.x * blockDim.x + threadIdx.x;
    if (i < n) p[i] = 0;
}

__global__ void k_count(const int* __restrict__ dst, int* degc, int e) {
    int i = blockIdx.x * blockDim.x + threadIdx.x;
    if (i < e) atomicAdd(&degc[dst[i]], 1);
}

__global__ void k_blocksum(const int* __restrict__ degc, int* __restrict__ bsum, int n) {
    int i = blockIdx.x * 256 + threadIdx.x;
    int v = (i < n) ? degc[i] : 0;
    #pragma unroll
    for (int off = 32; off > 0; off >>= 1) v += __shfl_down(v, off, 64);
    __shared__ int ws[4];
    if ((threadIdx.x & 63) == 0) ws[threadIdx.x >> 6] = v;
    __syncthreads();
    if (threadIdx.x == 0) bsum[blockIdx.x] = ws[0] + ws[1] + ws[2] + ws[3];
}

__global__ void k_scanbsum(int* bsum, int nb) {
    __shared__ int s[256];
    int t = threadIdx.x;
    int v = (t < nb) ? bsum[t] : 0;
    s[t] = v;
    __syncthreads();
    #pragma unroll
    for (int off = 1; off < 256; off <<= 1) {
        int u = (t >= off) ? s[t - off] : 0;
        __syncthreads();
        s[t] += u;
        __syncthreads();
    }
    if (t < nb) bsum[t] = (t == 0) ? 0 : s[t - 1];
}

__global__ void k_rowptr(const int* __restrict__ degc, const int* __restrict__ bsum,
                         int* __restrict__ row_ptr, int* __restrict__ cursor,
                         float* __restrict__ dinv, int n) {
    __shared__ int s[256];
    int i = blockIdx.x * 256 + threadIdx.x;
    int t = threadIdx.x;
    int d = (i < n) ? degc[i] : 0;
    s[t] = d;
    __syncthreads();
    #pragma unroll
    for (int off = 1; off < 256; off <<= 1) {
        int u = (t >= off) ? s[t - off] : 0;
        __syncthreads();
        s[t] += u;
        __syncthreads();
    }
    int ex = s[t] - d + bsum[blockIdx.x];
    if (i < n) {
        row_ptr[i] = ex;
        cursor[i]  = ex;
        dinv[i]    = rsqrtf(1.0f + (float)d);
        if (i == n - 1) row_ptr[n] = ex + d;
    }
}

__global__ void k_fill(const int* __restrict__ src, const int* __restrict__ dst,
                       const float* __restrict__ dinv, int* cursor,
                       int* __restrict__ csr_src, float* __restrict__ csr_w, int e) {
    int i = blockIdx.x * blockDim.x + threadIdx.x;
    if (i < e) {
        int s = src[i], d = dst[i];
        int p = atomicAdd(&cursor[d], 1);
        csr_src[p] = s;
        csr_w[p]   = dinv[s] * dinv[d];
    }
}

// ---------------- CSR gather-aggregate, float4 lanes ----------------

template<int W, int G, bool BIAS_RELU>
__global__ void k_agg4(const float* __restrict__ T, const float* __restrict__ dinv,
                       const int* __restrict__ row_ptr, const int* __restrict__ csr_src,
                       const float* __restrict__ csr_w, const float* __restrict__ b,
                       float* __restrict__ O, int n) {
    constexpr int W4 = W / 4;
    const int gpb = 256 / G;
    int g = blockIdx.x * gpb + threadIdx.x / G;
    int j = threadIdx.x % G;
    if (g >= n || j >= W4) return;

    const float4* T4 = (const float4*)T;
    float di = dinv[g];
    float  sw = di * di;
    float4 t  = T4[(size_t)g * W4 + j];
    float4 acc = make_float4(sw * t.x, sw * t.y, sw * t.z, sw * t.w);

    int lo = row_ptr[g], hi = row_ptr[g + 1];
    int   s_n = 0; float w_n = 0.0f;
    if (lo < hi) { s_n = csr_src[lo]; w_n = csr_w[lo]; }
    for (int k = lo; k < hi; ++k) {
        int s_c = s_n; float w_c = w_n;
        if (k + 1 < hi) { s_n = csr_src[k + 1]; w_n = csr_w[k + 1]; }
        float4 tv = T4[(size_t)s_c * W4 + j];
        acc.x += w_c * tv.x; acc.y += w_c * tv.y;
        acc.z += w_c * tv.z; acc.w += w_c * tv.w;
    }
    if (BIAS_RELU) {
        float4 bv = ((const float4*)b)[j];
        acc.x = fmaxf(acc.x + bv.x, 0.0f);
        acc.y = fmaxf(acc.y + bv.y, 0.0f);
        acc.z = fmaxf(acc.z + bv.z, 0.0f);
        acc.w = fmaxf(acc.w + bv.w, 0.0f);
    }
    ((float4*)O)[(size_t)g * W4 + j] = acc;
}

// ---------------- LDS-tiled register-blocked GEMM ----------------
// Block: 256 threads, NT-node tile, full DO columns, K chunked by KB.
// TC threads along cols (RC=DO/TC each), TN=256/TC along nodes (RN=NT/TN each).
// X tile staged coalesced into LDS (rows padded by P for bank spread).

template<int DI, int DO, int NT, int TC, int KB, int P, bool BIAS_RELU>
__global__ void k_gemm_t(const float* __restrict__ X, const float* __restrict__ W,
                         const float* __restrict__ b, float* __restrict__ H, int n) {
    constexpr int TN = 256 / TC;
    constexpr int RN = NT / TN;
    constexpr int RC = DO / TC;
    constexpr int KBP = KB + P;

    __shared__ float Xs[NT * KBP];
    __shared__ float Ws[KB * DO];

    const int g0 = blockIdx.x * NT;
    const int nvalid = min(n - g0, NT);
    const int tc = threadIdx.x % TC;
    const int tn = threadIdx.x / TC;

    float acc[RN][RC];
    #pragma unroll
    for (int r = 0; r < RN; ++r)
        #pragma unroll
        for (int c = 0; c < RC; ++c) acc[r][c] = 0.0f;

    for (int kb = 0; kb < DI; kb += KB) {
        if (kb) __syncthreads();
        // stage W chunk (contiguous, coalesced)
        {
            const float4* Wg = (const float4*)(W + (size_t)kb * DO);
            for (int i = threadIdx.x; i < KB * DO / 4; i += 256)
                ((float4*)Ws)[i] = Wg[i];
        }
        // stage X tile chunk (coalesced 16B within rows)
        {
            int total4 = nvalid * (KB / 4);
            for (int i = threadIdx.x; i < total4; i += 256) {
                int node = i / (KB / 4);
                int kk   = (i % (KB / 4)) * 4;
                float4 v = *(const float4*)(X + (size_t)(g0 + node) * DI + kb + kk);
                *(float4*)&Xs[node * KBP + kk] = v;
            }
        }
        __syncthreads();

        #pragma unroll
        for (int k0 = 0; k0 < KB; k0 += 4) {
            float4 xv[RN];
            #pragma unroll
            for (int r = 0; r < RN; ++r)
                xv[r] = *(float4*)&Xs[(tn * RN + r) * KBP + k0];
            #pragma unroll
            for (int kk = 0; kk < 4; ++kk) {
                float4 wv[RC / 4];
                #pragma unroll
                for (int c4 = 0; c4 < RC / 4; ++c4)
                    wv[c4] = *(float4*)&Ws[(k0 + kk) * DO + tc * RC + 4 * c4];
                #pragma unroll
                for (int r = 0; r < RN; ++r) {
                    float xs = ((const float*)&xv[r])[kk];
                    #pragma unroll
                    for (int c4 = 0; c4 < RC / 4; ++c4) {
                        acc[r][4 * c4 + 0] += xs * wv[c4].x;
                        acc[r][4 * c4 + 1] += xs * wv[c4].y;
                        acc[r][4 * c4 + 2] += xs * wv[c4].z;
                        acc[r][4 * c4 + 3] += xs * wv[c4].w;
                    }
                }
            }
        }
    }

    // epilogue
    float4 bv[RC / 4];
    if (BIAS_RELU) {
        #pragma unroll
        for (int c4 = 0; c4 < RC / 4; ++c4)
            bv[c4] = ((const float4*)b)[(tc * RC) / 4 + c4];
    }
    #pragma unroll
    for (int r = 0; r < RN; ++r) {
        int node = g0 + tn * RN + r;
        if (node < n) {
            float* hr = H + (size_t)node * DO + tc * RC;
            #pragma unroll
            for (int c4 = 0; c4 < RC / 4; ++c4) {
                float4 v;
                v.x = acc[r][4 * c4 + 0]; v.y = acc[r][4 * c4 + 1];
                v.z = acc[r][4 * c4 + 2]; v.w = acc[r][4 * c4 + 3];
                if (BIAS_RELU) {
                    v.x = fmaxf(v.x + bv[c4].x, 0.0f);
                    v.y = fmaxf(v.y + bv[c4].y, 0.0f);
                    v.z = fmaxf(v.z + bv[c4].z, 0.0f);
                    v.w = fmaxf(v.w + bv[c4].w, 0.0f);
                }
                ((float4*)hr)[c4] = v;
            }
        }
    }
}

// ---------------- MLP head ----------------

__global__ void k_mlp(const float* __restrict__ O3,
                      const float* __restrict__ Wf1, const float* __restrict__ bf1,
                      const float* __restrict__ Wf2, const float* __restrict__ bf2,
                      float* __restrict__ out, int n) {
    __shared__ float W1s[32 * 16];
    __shared__ float b1s[16];
    __shared__ float W2s[16];
    __shared__ float b2s;
    for (int t = threadIdx.x; t < 32 * 16; t += blockDim.x) W1s[t] = Wf1[t];
    if (threadIdx.x < 16) { b1s[threadIdx.x] = bf1[threadIdx.x]; W2s[threadIdx.x] = Wf2[threadIdx.x]; }
    if (threadIdx.x == 0) b2s = bf2[0];
    __syncthreads();

    for (int node = blockIdx.x * blockDim.x + threadIdx.x; node < n;
         node += gridDim.x * blockDim.x) {
        float h[16];
        #pragma unroll
        for (int j = 0; j < 16; ++j) h[j] = b1s[j];
        const float* xr = O3 + (size_t)node * 32;
        #pragma unroll
        for (int k = 0; k < 32; ++k) {
            float xv = xr[k];
            #pragma unroll
            for (int j = 0; j < 16; ++j) h[j] += xv * W1s[k * 16 + j];
        }
        float acc = b2s;
        #pragma unroll
        for (int j = 0; j < 16; ++j) acc += fmaxf(h[j], 0.0f) * W2s[j];
        out[node] = 1.0f / (1.0f + expf(-acc));
    }
}

// ---------------- launch ----------------

extern "C" void kernel_launch(void* const* d_in, const int* in_sizes, int n_in,
                              void* d_out, int out_size, void* d_ws, size_t ws_size,
                              hipStream_t stream) {
    const float* x   = (const float*)d_in[0];
    const int*   ei  = (const int*)d_in[1];
    const float* W1  = (const float*)d_in[2];
    const float* b1  = (const float*)d_in[3];
    const float* W2  = (const float*)d_in[4];
    const float* b2  = (const float*)d_in[5];
    const float* W3  = (const float*)d_in[6];
    const float* b3  = (const float*)d_in[7];
    const float* Wf1 = (const float*)d_in[8];
    const float* bf1 = (const float*)d_in[9];
    const float* Wf2 = (const float*)d_in[10];
    const float* bf2 = (const float*)d_in[11];
    float* out = (float*)d_out;

    const int N = N_NODES, E = N_EDGES;
    const int* src = ei;
    const int* dst = ei + E;

    char* w = (char*)d_ws;
    float* dinv    = (float*)w;                     w += (size_t)N * 4;
    int*   degc    = (int*)w;                       w += (size_t)N * 4;
    int*   row_ptr = (int*)w;                       w += (size_t)(N + 4) * 4;
    int*   cursor  = (int*)w;                       w += (size_t)N * 4;
    int*   bsum    = (int*)w;                       w += (size_t)256 * 4;
    int*   csr_src = (int*)w;                       w += (size_t)E * 4;
    float* csr_w   = (float*)w;                     w += (size_t)E * 4;
    float* bufA    = (float*)w;                     w += (size_t)N * 64 * 4;
    float* bufB    = (float*)w;                                              // N*128

    const int B  = 256;
    const int NB = (N + B - 1) / B;        // 196
    const int GT = (N + 63) / 64;          // 782 GEMM tiles

    // ---- CSR build ----
    k_zero     <<<NB, B, 0, stream>>>(degc, N);
    k_count    <<<(E + B - 1) / B, B, 0, stream>>>(dst, degc, E);
    k_blocksum <<<NB, B, 0, stream>>>(degc, bsum, N);
    k_scanbsum <<<1, B, 0, stream>>>(bsum, NB);
    k_rowptr   <<<NB, B, 0, stream>>>(degc, bsum, row_ptr, cursor, dinv, N);
    k_fill     <<<(E + B - 1) / B, B, 0, stream>>>(src, dst, dinv, cursor, csr_src, csr_w, E);

    // ---- layer 1: aggregate x at 44 dims, then GEMM 44->128 (+b1, relu) ----
    k_agg4<44, 16, false><<<(N * 16 + B - 1) / B, B, 0, stream>>>(
        x, dinv, row_ptr, csr_src, csr_w, nullptr, bufA, N);
    // DI=44 DO=128 NT=64 TC=16 KB=44 P=0 : RN=4 RC=8, LDS 11.3+22.5 KB
    k_gemm_t<44, 128, 64, 16, 44, 0, true><<<GT, B, 0, stream>>>(bufA, W1, b1, bufB, N);

    // ---- layer 2: GEMM 128->64, aggregate at 64 (+b2, relu) ----
    // DI=128 DO=64 NT=64 TC=16 KB=64 P=4 : RN=4 RC=4, LDS 17.4+16 KB
    k_gemm_t<128, 64, 64, 16, 64, 4, false><<<GT, B, 0, stream>>>(bufB, W2, nullptr, bufA, N);
    k_agg4<64, 16, true><<<(N * 16 + B - 1) / B, B, 0, stream>>>(
        bufA, dinv, row_ptr, csr_src, csr_w, b2, bufB, N);

    // ---- layer 3: GEMM 64->32, aggregate at 32 (+b3, relu) ----
    // DI=64 DO=32 NT=64 TC=8 KB=64 P=4 : RN=2 RC=4, LDS 17.4+8 KB
    k_gemm_t<64, 32, 64, 8, 64, 4, false><<<GT, B, 0, stream>>>(bufB, W3, nullptr, bufA, N);
    k_agg4<32, 8, true><<<(N * 8 + B - 1) / B, B, 0, stream>>>(
        bufA, dinv, row_ptr, csr_src, csr_w, b3, bufB, N);

    // ---- MLP head ----
    k_mlp<<<NB, B, 0, stream>>>(bufB, Wf1, bf1, Wf2, bf2, out, N);
}

// Round 6
// 641.114 us; speedup vs baseline: 1.1288x; 1.1288x over previous
//
#include <hip/hip_runtime.h>
#include <hip/hip_bf16.h>
#include <math.h>

#define N_NODES 50000
#define N_EDGES 600000
#define D_IN    44

// ---------------- CSR build ----------------

__global__ void k_zero(int* p, int n) {
    int i = blockIdx.x * blockDim.x + threadIdx.x;
    if (i < n) p[i] = 0;
}

__global__ void k_count(const int* __restrict__ dst, int* degc, int e) {
    int i = blockIdx.x * blockDim.x + threadIdx.x;
    if (i < e) atomicAdd(&degc[dst[i]], 1);
}

__global__ void k_blocksum(const int* __restrict__ degc, int* __restrict__ bsum, int n) {
    int i = blockIdx.x * 256 + threadIdx.x;
    int v = (i < n) ? degc[i] : 0;
    #pragma unroll
    for (int off = 32; off > 0; off >>= 1) v += __shfl_down(v, off, 64);
    __shared__ int ws[4];
    if ((threadIdx.x & 63) == 0) ws[threadIdx.x >> 6] = v;
    __syncthreads();
    if (threadIdx.x == 0) bsum[blockIdx.x] = ws[0] + ws[1] + ws[2] + ws[3];
}

__global__ void k_scanbsum(int* bsum, int nb) {
    __shared__ int s[256];
    int t = threadIdx.x;
    int v = (t < nb) ? bsum[t] : 0;
    s[t] = v;
    __syncthreads();
    #pragma unroll
    for (int off = 1; off < 256; off <<= 1) {
        int u = (t >= off) ? s[t - off] : 0;
        __syncthreads();
        s[t] += u;
        __syncthreads();
    }
    if (t < nb) bsum[t] = (t == 0) ? 0 : s[t - 1];
}

__global__ void k_rowptr(const int* __restrict__ degc, const int* __restrict__ bsum,
                         int* __restrict__ row_ptr, int* __restrict__ cursor,
                         float* __restrict__ dinv, int n) {
    __shared__ int s[256];
    int i = blockIdx.x * 256 + threadIdx.x;
    int t = threadIdx.x;
    int d = (i < n) ? degc[i] : 0;
    s[t] = d;
    __syncthreads();
    #pragma unroll
    for (int off = 1; off < 256; off <<= 1) {
        int u = (t >= off) ? s[t - off] : 0;
        __syncthreads();
        s[t] += u;
        __syncthreads();
    }
    int ex = s[t] - d + bsum[blockIdx.x];
    if (i < n) {
        row_ptr[i] = ex;
        cursor[i]  = ex;
        dinv[i]    = rsqrtf(1.0f + (float)d);
        if (i == n - 1) row_ptr[n] = ex + d;
    }
}

__global__ void k_fill(const int* __restrict__ src, const int* __restrict__ dst,
                       const float* __restrict__ dinv, int* cursor,
                       int* __restrict__ csr_src, float* __restrict__ csr_w, int e) {
    int i = blockIdx.x * blockDim.x + threadIdx.x;
    if (i < e) {
        int s = src[i], d = dst[i];
        int p = atomicAdd(&cursor[d], 1);
        csr_src[p] = s;
        csr_w[p]   = dinv[s] * dinv[d];
    }
}

// ---------------- CSR gather-aggregate, float4 lanes ----------------

template<int W, int G, bool BIAS_RELU>
__global__ void k_agg4(const float* __restrict__ T, const float* __restrict__ dinv,
                       const int* __restrict__ row_ptr, const int* __restrict__ csr_src,
                       const float* __restrict__ csr_w, const float* __restrict__ b,
                       float* __restrict__ O, int n) {
    constexpr int W4 = W / 4;
    const int gpb = 256 / G;
    int g = blockIdx.x * gpb + threadIdx.x / G;
    int j = threadIdx.x % G;
    if (g >= n || j >= W4) return;

    const float4* T4 = (const float4*)T;
    float di = dinv[g];
    float  sw = di * di;
    float4 t  = T4[(size_t)g * W4 + j];
    float4 acc = make_float4(sw * t.x, sw * t.y, sw * t.z, sw * t.w);

    int lo = row_ptr[g], hi = row_ptr[g + 1];
    int   s_n = 0; float w_n = 0.0f;
    if (lo < hi) { s_n = csr_src[lo]; w_n = csr_w[lo]; }
    for (int k = lo; k < hi; ++k) {
        int s_c = s_n; float w_c = w_n;
        if (k + 1 < hi) { s_n = csr_src[k + 1]; w_n = csr_w[k + 1]; }
        float4 tv = T4[(size_t)s_c * W4 + j];
        acc.x += w_c * tv.x; acc.y += w_c * tv.y;
        acc.z += w_c * tv.z; acc.w += w_c * tv.w;
    }
    if (BIAS_RELU) {
        float4 bv = ((const float4*)b)[j];
        acc.x = fmaxf(acc.x + bv.x, 0.0f);
        acc.y = fmaxf(acc.y + bv.y, 0.0f);
        acc.z = fmaxf(acc.z + bv.z, 0.0f);
        acc.w = fmaxf(acc.w + bv.w, 0.0f);
    }
    ((float4*)O)[(size_t)g * W4 + j] = acc;
}

// ---------------- LDS-tiled register-blocked GEMM (no address-taken reg arrays) ----
// Block: 256 threads, NT nodes, DOB columns (ct0 = blockIdx.y*DOB), K chunked by KB.
// TC threads along cols, RC=DOB/TC=4 cols/thread; TN=256/TC node-threads, RN=NT/TN.

template<int DI, int DO, int DOB, int NT, int TC, int KB, int P, bool BR>
__global__ void k_gemm_t(const float* __restrict__ X, const float* __restrict__ W,
                         const float* __restrict__ b, float* __restrict__ H, int n) {
    constexpr int TN  = 256 / TC;
    constexpr int RN  = NT / TN;
    constexpr int KBP = KB + P;
    static_assert(DOB / TC == 4, "RC must be 4");

    __shared__ float Xs[NT * KBP];
    __shared__ float Ws[KB * DOB];

    const int g0     = blockIdx.x * NT;
    const int ct0    = blockIdx.y * DOB;
    const int nvalid = min(n - g0, NT);
    const int tc     = threadIdx.x % TC;
    const int tn     = threadIdx.x / TC;

    float acc[RN][4];
    #pragma unroll
    for (int r = 0; r < RN; ++r) {
        acc[r][0] = 0.0f; acc[r][1] = 0.0f; acc[r][2] = 0.0f; acc[r][3] = 0.0f;
    }

    for (int kb = 0; kb < DI; kb += KB) {
        if (kb) __syncthreads();
        // stage W chunk [KB x DOB], coalesced
        for (int i = threadIdx.x; i < KB * (DOB / 4); i += 256) {
            int row = i / (DOB / 4), c4 = i % (DOB / 4);
            float4 v = *(const float4*)(W + (size_t)(kb + row) * DO + ct0 + 4 * c4);
            *(float4*)&Ws[row * DOB + 4 * c4] = v;
        }
        // stage X tile chunk [nvalid x KB], coalesced 16B
        for (int i = threadIdx.x; i < nvalid * (KB / 4); i += 256) {
            int node = i / (KB / 4), k4 = i % (KB / 4);
            float4 v = *(const float4*)(X + (size_t)(g0 + node) * DI + kb + 4 * k4);
            *(float4*)&Xs[node * KBP + 4 * k4] = v;
        }
        __syncthreads();

        #pragma unroll
        for (int k0 = 0; k0 < KB; k0 += 4) {
            float4 w0 = *(const float4*)&Ws[(k0 + 0) * DOB + tc * 4];
            float4 w1 = *(const float4*)&Ws[(k0 + 1) * DOB + tc * 4];
            float4 w2 = *(const float4*)&Ws[(k0 + 2) * DOB + tc * 4];
            float4 w3 = *(const float4*)&Ws[(k0 + 3) * DOB + tc * 4];
            #pragma unroll
            for (int r = 0; r < RN; ++r) {
                float4 xv = *(const float4*)&Xs[(tn * RN + r) * KBP + k0];
                acc[r][0] += xv.x * w0.x; acc[r][1] += xv.x * w0.y;
                acc[r][2] += xv.x * w0.z; acc[r][3] += xv.x * w0.w;
                acc[r][0] += xv.y * w1.x; acc[r][1] += xv.y * w1.y;
                acc[r][2] += xv.y * w1.z; acc[r][3] += xv.y * w1.w;
                acc[r][0] += xv.z * w2.x; acc[r][1] += xv.z * w2.y;
                acc[r][2] += xv.z * w2.z; acc[r][3] += xv.z * w2.w;
                acc[r][0] += xv.w * w3.x; acc[r][1] += xv.w * w3.y;
                acc[r][2] += xv.w * w3.z; acc[r][3] += xv.w * w3.w;
            }
        }
    }

    float4 bv = make_float4(0.f, 0.f, 0.f, 0.f);
    if (BR) bv = *(const float4*)(b + ct0 + tc * 4);

    #pragma unroll
    for (int r = 0; r < RN; ++r) {
        int node = g0 + tn * RN + r;
        if (node < n) {
            float4 v;
            v.x = acc[r][0]; v.y = acc[r][1]; v.z = acc[r][2]; v.w = acc[r][3];
            if (BR) {
                v.x = fmaxf(v.x + bv.x, 0.0f);
                v.y = fmaxf(v.y + bv.y, 0.0f);
                v.z = fmaxf(v.z + bv.z, 0.0f);
                v.w = fmaxf(v.w + bv.w, 0.0f);
            }
            *(float4*)(H + (size_t)node * DO + ct0 + tc * 4) = v;
        }
    }
}

// ---------------- MLP head ----------------

__global__ void k_mlp(const float* __restrict__ O3,
                      const float* __restrict__ Wf1, const float* __restrict__ bf1,
                      const float* __restrict__ Wf2, const float* __restrict__ bf2,
                      float* __restrict__ out, int n) {
    __shared__ float W1s[32 * 16];
    __shared__ float b1s[16];
    __shared__ float W2s[16];
    __shared__ float b2s;
    for (int t = threadIdx.x; t < 32 * 16; t += blockDim.x) W1s[t] = Wf1[t];
    if (threadIdx.x < 16) { b1s[threadIdx.x] = bf1[threadIdx.x]; W2s[threadIdx.x] = Wf2[threadIdx.x]; }
    if (threadIdx.x == 0) b2s = bf2[0];
    __syncthreads();

    for (int node = blockIdx.x * blockDim.x + threadIdx.x; node < n;
         node += gridDim.x * blockDim.x) {
        float h[16];
        #pragma unroll
        for (int j = 0; j < 16; ++j) h[j] = b1s[j];
        const float* xr = O3 + (size_t)node * 32;
        #pragma unroll
        for (int k = 0; k < 32; ++k) {
            float xv = xr[k];
            #pragma unroll
            for (int j = 0; j < 16; ++j) h[j] += xv * W1s[k * 16 + j];
        }
        float acc = b2s;
        #pragma unroll
        for (int j = 0; j < 16; ++j) acc += fmaxf(h[j], 0.0f) * W2s[j];
        out[node] = 1.0f / (1.0f + expf(-acc));
    }
}

// ---------------- launch ----------------

extern "C" void kernel_launch(void* const* d_in, const int* in_sizes, int n_in,
                              void* d_out, int out_size, void* d_ws, size_t ws_size,
                              hipStream_t stream) {
    const float* x   = (const float*)d_in[0];
    const int*   ei  = (const int*)d_in[1];
    const float* W1  = (const float*)d_in[2];
    const float* b1  = (const float*)d_in[3];
    const float* W2  = (const float*)d_in[4];
    const float* b2  = (const float*)d_in[5];
    const float* W3  = (const float*)d_in[6];
    const float* b3  = (const float*)d_in[7];
    const float* Wf1 = (const float*)d_in[8];
    const float* bf1 = (const float*)d_in[9];
    const float* Wf2 = (const float*)d_in[10];
    const float* bf2 = (const float*)d_in[11];
    float* out = (float*)d_out;

    const int N = N_NODES, E = N_EDGES;
    const int* src = ei;
    const int* dst = ei + E;

    char* w = (char*)d_ws;
    float* dinv    = (float*)w;                     w += (size_t)N * 4;
    int*   degc    = (int*)w;                       w += (size_t)N * 4;
    int*   row_ptr = (int*)w;                       w += (size_t)(N + 4) * 4;
    int*   cursor  = (int*)w;                       w += (size_t)N * 4;
    int*   bsum    = (int*)w;                       w += (size_t)256 * 4;
    int*   csr_src = (int*)w;                       w += (size_t)E * 4;
    float* csr_w   = (float*)w;                     w += (size_t)E * 4;
    float* bufA    = (float*)w;                     w += (size_t)N * 64 * 4;
    float* bufB    = (float*)w;                                              // N*128

    const int B  = 256;
    const int NB = (N + B - 1) / B;        // 196
    const int GT = (N + 63) / 64;          // 782 GEMM node-tiles

    // ---- CSR build ----
    k_zero     <<<NB, B, 0, stream>>>(degc, N);
    k_count    <<<(E + B - 1) / B, B, 0, stream>>>(dst, degc, E);
    k_blocksum <<<NB, B, 0, stream>>>(degc, bsum, N);
    k_scanbsum <<<1, B, 0, stream>>>(bsum, NB);
    k_rowptr   <<<NB, B, 0, stream>>>(degc, bsum, row_ptr, cursor, dinv, N);
    k_fill     <<<(E + B - 1) / B, B, 0, stream>>>(src, dst, dinv, cursor, csr_src, csr_w, E);

    // ---- layer 1: aggregate x at 44 dims, then GEMM 44->128 (+b1, relu) ----
    k_agg4<44, 16, false><<<(N * 16 + B - 1) / B, B, 0, stream>>>(
        x, dinv, row_ptr, csr_src, csr_w, nullptr, bufA, N);
    // DI=44 DO=128 DOB=64 NT=64 TC=16 KB=44 P=4 : LDS 12.3+11.3 KB, grid y=2
    k_gemm_t<44, 128, 64, 64, 16, 44, 4, true><<<dim3(GT, 2), B, 0, stream>>>(bufA, W1, b1, bufB, N);

    // ---- layer 2: GEMM 128->64, aggregate at 64 (+b2, relu) ----
    // DI=128 DO=64 DOB=64 NT=64 TC=16 KB=64 P=4 : LDS 17.4+16.4 KB
    k_gemm_t<128, 64, 64, 64, 16, 64, 4, false><<<dim3(GT, 1), B, 0, stream>>>(bufB, W2, nullptr, bufA, N);
    k_agg4<64, 16, true><<<(N * 16 + B - 1) / B, B, 0, stream>>>(
        bufA, dinv, row_ptr, csr_src, csr_w, b2, bufB, N);

    // ---- layer 3: GEMM 64->32, aggregate at 32 (+b3, relu) ----
    // DI=64 DO=32 DOB=32 NT=64 TC=8 KB=64 P=4 : LDS 17.4+8.2 KB
    k_gemm_t<64, 32, 32, 64, 8, 64, 4, false><<<dim3(GT, 1), B, 0, stream>>>(bufB, W3, nullptr, bufA, N);
    k_agg4<32, 8, true><<<(N * 8 + B - 1) / B, B, 0, stream>>>(
        bufA, dinv, row_ptr, csr_src, csr_w, b3, bufB, N);

    // ---- MLP head ----
    k_mlp<<<NB, B, 0, stream>>>(bufB, Wf1, bf1, Wf2, bf2, out, N);
}

// Round 7
// 370.095 us; speedup vs baseline: 1.9554x; 1.7323x over previous
//
#include <hip/hip_runtime.h>
#include <hip/hip_bf16.h>
#include <math.h>

#define N_NODES 50000
#define N_EDGES 600000
#define D_IN    44

// ---------------- CSR build ----------------

__global__ void k_zero(int* p, int n) {
    int i = blockIdx.x * blockDim.x + threadIdx.x;
    if (i < n) p[i] = 0;
}

__global__ void k_count(const int* __restrict__ dst, int* degc, int e) {
    int i = blockIdx.x * blockDim.x + threadIdx.x;
    if (i < e) atomicAdd(&degc[dst[i]], 1);
}

__global__ void k_blocksum(const int* __restrict__ degc, int* __restrict__ bsum, int n) {
    int i = blockIdx.x * 256 + threadIdx.x;
    int v = (i < n) ? degc[i] : 0;
    #pragma unroll
    for (int off = 32; off > 0; off >>= 1) v += __shfl_down(v, off, 64);
    __shared__ int ws[4];
    if ((threadIdx.x & 63) == 0) ws[threadIdx.x >> 6] = v;
    __syncthreads();
    if (threadIdx.x == 0) bsum[blockIdx.x] = ws[0] + ws[1] + ws[2] + ws[3];
}

__global__ void k_scanbsum(int* bsum, int nb) {
    __shared__ int s[256];
    int t = threadIdx.x;
    int v = (t < nb) ? bsum[t] : 0;
    s[t] = v;
    __syncthreads();
    #pragma unroll
    for (int off = 1; off < 256; off <<= 1) {
        int u = (t >= off) ? s[t - off] : 0;
        __syncthreads();
        s[t] += u;
        __syncthreads();
    }
    if (t < nb) bsum[t] = (t == 0) ? 0 : s[t - 1];
}

__global__ void k_rowptr(const int* __restrict__ degc, const int* __restrict__ bsum,
                         int* __restrict__ row_ptr, int* __restrict__ cursor,
                         float* __restrict__ dinv, int n) {
    __shared__ int s[256];
    int i = blockIdx.x * 256 + threadIdx.x;
    int t = threadIdx.x;
    int d = (i < n) ? degc[i] : 0;
    s[t] = d;
    __syncthreads();
    #pragma unroll
    for (int off = 1; off < 256; off <<= 1) {
        int u = (t >= off) ? s[t - off] : 0;
        __syncthreads();
        s[t] += u;
        __syncthreads();
    }
    int ex = s[t] - d + bsum[blockIdx.x];
    if (i < n) {
        row_ptr[i] = ex;
        cursor[i]  = ex;
        dinv[i]    = rsqrtf(1.0f + (float)d);
        if (i == n - 1) row_ptr[n] = ex + d;
    }
}

__global__ void k_fill(const int* __restrict__ src, const int* __restrict__ dst,
                       const float* __restrict__ dinv, int* cursor,
                       int* __restrict__ csr_src, float* __restrict__ csr_w, int e) {
    int i = blockIdx.x * blockDim.x + threadIdx.x;
    if (i < e) {
        int s = src[i], d = dst[i];
        int p = atomicAdd(&cursor[d], 1);
        csr_src[p] = s;
        csr_w[p]   = dinv[s] * dinv[d];
    }
}

// ---------------- CSR gather-aggregate, float4 lanes ----------------

template<int W, int G, bool BIAS_RELU>
__global__ void k_agg4(const float* __restrict__ T, const float* __restrict__ dinv,
                       const int* __restrict__ row_ptr, const int* __restrict__ csr_src,
                       const float* __restrict__ csr_w, const float* __restrict__ b,
                       float* __restrict__ O, int n) {
    constexpr int W4 = W / 4;
    const int gpb = 256 / G;
    int g = blockIdx.x * gpb + threadIdx.x / G;
    int j = threadIdx.x % G;
    if (g >= n || j >= W4) return;

    const float4* T4 = (const float4*)T;
    float di = dinv[g];
    float  sw = di * di;
    float4 t  = T4[(size_t)g * W4 + j];
    float4 acc = make_float4(sw * t.x, sw * t.y, sw * t.z, sw * t.w);

    int lo = row_ptr[g], hi = row_ptr[g + 1];
    int   s_n = 0; float w_n = 0.0f;
    if (lo < hi) { s_n = csr_src[lo]; w_n = csr_w[lo]; }
    for (int k = lo; k < hi; ++k) {
        int s_c = s_n; float w_c = w_n;
        if (k + 1 < hi) { s_n = csr_src[k + 1]; w_n = csr_w[k + 1]; }
        float4 tv = T4[(size_t)s_c * W4 + j];
        acc.x += w_c * tv.x; acc.y += w_c * tv.y;
        acc.z += w_c * tv.z; acc.w += w_c * tv.w;
    }
    if (BIAS_RELU) {
        float4 bv = ((const float4*)b)[j];
        acc.x = fmaxf(acc.x + bv.x, 0.0f);
        acc.y = fmaxf(acc.y + bv.y, 0.0f);
        acc.z = fmaxf(acc.z + bv.z, 0.0f);
        acc.w = fmaxf(acc.w + bv.w, 0.0f);
    }
    ((float4*)O)[(size_t)g * W4 + j] = acc;
}

// ---------------- register-blocked GEMM (round-4 proven-clean shape) ----------------
// One thread = one node x CT columns. Column-split on blockIdx.x (fast-varying,
// dispatch-adjacent blocks share the same node rows -> L2 locality).
// Node tile on blockIdx.y.

template<int DI, int DO, int CT, bool BIAS_RELU>
__global__ void k_gemm(const float* __restrict__ X, const float* __restrict__ W,
                       const float* __restrict__ b, float* __restrict__ H, int n) {
    __shared__ float Ws[DI * CT];
    const int ct0 = blockIdx.x * CT;
    for (int i = threadIdx.x; i < DI * CT; i += blockDim.x) {
        int k = i / CT, c = i % CT;
        Ws[i] = W[k * DO + ct0 + c];
    }
    __syncthreads();

    int node = blockIdx.y * blockDim.x + threadIdx.x;
    if (node >= n) return;

    float acc[CT];
    #pragma unroll
    for (int c = 0; c < CT; ++c) acc[c] = BIAS_RELU ? b[ct0 + c] : 0.0f;

    const float4* xr = (const float4*)(X + (size_t)node * DI);
    #pragma unroll
    for (int k0 = 0; k0 < DI / 4; ++k0) {
        float4 xv = xr[k0];
        #pragma unroll
        for (int c = 0; c < CT; ++c) acc[c] += xv.x * Ws[(k0 * 4 + 0) * CT + c];
        #pragma unroll
        for (int c = 0; c < CT; ++c) acc[c] += xv.y * Ws[(k0 * 4 + 1) * CT + c];
        #pragma unroll
        for (int c = 0; c < CT; ++c) acc[c] += xv.z * Ws[(k0 * 4 + 2) * CT + c];
        #pragma unroll
        for (int c = 0; c < CT; ++c) acc[c] += xv.w * Ws[(k0 * 4 + 3) * CT + c];
    }

    float* hr = H + (size_t)node * DO + ct0;
    #pragma unroll
    for (int c4 = 0; c4 < CT / 4; ++c4) {
        float4 v;
        v.x = acc[c4 * 4 + 0]; v.y = acc[c4 * 4 + 1];
        v.z = acc[c4 * 4 + 2]; v.w = acc[c4 * 4 + 3];
        if (BIAS_RELU) {
            v.x = fmaxf(v.x, 0.0f); v.y = fmaxf(v.y, 0.0f);
            v.z = fmaxf(v.z, 0.0f); v.w = fmaxf(v.w, 0.0f);
        }
        ((float4*)hr)[c4] = v;
    }
}

// ---------------- MLP head ----------------

__global__ void k_mlp(const float* __restrict__ O3,
                      const float* __restrict__ Wf1, const float* __restrict__ bf1,
                      const float* __restrict__ Wf2, const float* __restrict__ bf2,
                      float* __restrict__ out, int n) {
    __shared__ float W1s[32 * 16];
    __shared__ float b1s[16];
    __shared__ float W2s[16];
    __shared__ float b2s;
    for (int t = threadIdx.x; t < 32 * 16; t += blockDim.x) W1s[t] = Wf1[t];
    if (threadIdx.x < 16) { b1s[threadIdx.x] = bf1[threadIdx.x]; W2s[threadIdx.x] = Wf2[threadIdx.x]; }
    if (threadIdx.x == 0) b2s = bf2[0];
    __syncthreads();

    for (int node = blockIdx.x * blockDim.x + threadIdx.x; node < n;
         node += gridDim.x * blockDim.x) {
        float h[16];
        #pragma unroll
        for (int j = 0; j < 16; ++j) h[j] = b1s[j];
        const float* xr = O3 + (size_t)node * 32;
        #pragma unroll
        for (int k = 0; k < 32; ++k) {
            float xv = xr[k];
            #pragma unroll
            for (int j = 0; j < 16; ++j) h[j] += xv * W1s[k * 16 + j];
        }
        float acc = b2s;
        #pragma unroll
        for (int j = 0; j < 16; ++j) acc += fmaxf(h[j], 0.0f) * W2s[j];
        out[node] = 1.0f / (1.0f + expf(-acc));
    }
}

// ---------------- launch ----------------

extern "C" void kernel_launch(void* const* d_in, const int* in_sizes, int n_in,
                              void* d_out, int out_size, void* d_ws, size_t ws_size,
                              hipStream_t stream) {
    const float* x   = (const float*)d_in[0];
    const int*   ei  = (const int*)d_in[1];
    const float* W1  = (const float*)d_in[2];
    const float* b1  = (const float*)d_in[3];
    const float* W2  = (const float*)d_in[4];
    const float* b2  = (const float*)d_in[5];
    const float* W3  = (const float*)d_in[6];
    const float* b3  = (const float*)d_in[7];
    const float* Wf1 = (const float*)d_in[8];
    const float* bf1 = (const float*)d_in[9];
    const float* Wf2 = (const float*)d_in[10];
    const float* bf2 = (const float*)d_in[11];
    float* out = (float*)d_out;

    const int N = N_NODES, E = N_EDGES;
    const int* src = ei;
    const int* dst = ei + E;

    char* w = (char*)d_ws;
    float* dinv    = (float*)w;                     w += (size_t)N * 4;
    int*   degc    = (int*)w;                       w += (size_t)N * 4;
    int*   row_ptr = (int*)w;                       w += (size_t)(N + 4) * 4;
    int*   cursor  = (int*)w;                       w += (size_t)N * 4;
    int*   bsum    = (int*)w;                       w += (size_t)256 * 4;
    int*   csr_src = (int*)w;                       w += (size_t)E * 4;
    float* csr_w   = (float*)w;                     w += (size_t)E * 4;
    float* bufA    = (float*)w;                     w += (size_t)N * 64 * 4;
    float* bufB    = (float*)w;                                              // N*128

    const int B  = 256;
    const int NB = (N + B - 1) / B;        // 196

    // ---- CSR build ----
    k_zero     <<<NB, B, 0, stream>>>(degc, N);
    k_count    <<<(E + B - 1) / B, B, 0, stream>>>(dst, degc, E);
    k_blocksum <<<NB, B, 0, stream>>>(degc, bsum, N);
    k_scanbsum <<<1, B, 0, stream>>>(bsum, NB);
    k_rowptr   <<<NB, B, 0, stream>>>(degc, bsum, row_ptr, cursor, dinv, N);
    k_fill     <<<(E + B - 1) / B, B, 0, stream>>>(src, dst, dinv, cursor, csr_src, csr_w, E);

    // ---- layer 1: aggregate x at 44 dims, then GEMM 44->128 (+b1, relu) ----
    k_agg4<44, 16, false><<<(N * 16 + B - 1) / B, B, 0, stream>>>(
        x, dinv, row_ptr, csr_src, csr_w, nullptr, bufA, N);
    // CT=16, 8 column-blocks -> 1568 blocks
    k_gemm<44, 128, 16, true><<<dim3(8, NB), B, 0, stream>>>(bufA, W1, b1, bufB, N);

    // ---- layer 2: GEMM 128->64, aggregate at 64 (+b2, relu) ----
    // CT=16, 4 column-blocks -> 784 blocks
    k_gemm<128, 64, 16, false><<<dim3(4, NB), B, 0, stream>>>(bufB, W2, nullptr, bufA, N);
    k_agg4<64, 16, true><<<(N * 16 + B - 1) / B, B, 0, stream>>>(
        bufA, dinv, row_ptr, csr_src, csr_w, b2, bufB, N);

    // ---- layer 3: GEMM 64->32, aggregate at 32 (+b3, relu) ----
    // CT=8, 4 column-blocks -> 784 blocks
    k_gemm<64, 32, 8, false><<<dim3(4, NB), B, 0, stream>>>(bufB, W3, nullptr, bufA, N);
    k_agg4<32, 8, true><<<(N * 8 + B - 1) / B, B, 0, stream>>>(
        bufA, dinv, row_ptr, csr_src, csr_w, b3, bufB, N);

    // ---- MLP head ----
    k_mlp<<<NB, B, 0, stream>>>(bufB, Wf1, bf1, Wf2, bf2, out, N);
}

// Round 8
// 329.806 us; speedup vs baseline: 2.1943x; 1.1222x over previous
//
#include <hip/hip_runtime.h>
#include <hip/hip_bf16.h>
#include <math.h>

#define N_NODES 50000
#define N_EDGES 600000
#define D_IN    44

// ---------------- CSR build ----------------

__global__ void k_zero(int* p, int n) {
    int i = blockIdx.x * blockDim.x + threadIdx.x;
    if (i < n) p[i] = 0;
}

__global__ void k_count(const int* __restrict__ dst, int* degc, int e) {
    int i = blockIdx.x * blockDim.x + threadIdx.x;
    if (i < e) atomicAdd(&degc[dst[i]], 1);
}

__global__ void k_blocksum(const int* __restrict__ degc, int* __restrict__ bsum, int n) {
    int i = blockIdx.x * 256 + threadIdx.x;
    int v = (i < n) ? degc[i] : 0;
    #pragma unroll
    for (int off = 32; off > 0; off >>= 1) v += __shfl_down(v, off, 64);
    __shared__ int ws[4];
    if ((threadIdx.x & 63) == 0) ws[threadIdx.x >> 6] = v;
    __syncthreads();
    if (threadIdx.x == 0) bsum[blockIdx.x] = ws[0] + ws[1] + ws[2] + ws[3];
}

__global__ void k_scanbsum(int* bsum, int nb) {
    __shared__ int s[256];
    int t = threadIdx.x;
    int v = (t < nb) ? bsum[t] : 0;
    s[t] = v;
    __syncthreads();
    #pragma unroll
    for (int off = 1; off < 256; off <<= 1) {
        int u = (t >= off) ? s[t - off] : 0;
        __syncthreads();
        s[t] += u;
        __syncthreads();
    }
    if (t < nb) bsum[t] = (t == 0) ? 0 : s[t - 1];
}

__global__ void k_rowptr(const int* __restrict__ degc, const int* __restrict__ bsum,
                         int* __restrict__ row_ptr, int* __restrict__ cursor,
                         float* __restrict__ dinv, int n) {
    __shared__ int s[256];
    int i = blockIdx.x * 256 + threadIdx.x;
    int t = threadIdx.x;
    int d = (i < n) ? degc[i] : 0;
    s[t] = d;
    __syncthreads();
    #pragma unroll
    for (int off = 1; off < 256; off <<= 1) {
        int u = (t >= off) ? s[t - off] : 0;
        __syncthreads();
        s[t] += u;
        __syncthreads();
    }
    int ex = s[t] - d + bsum[blockIdx.x];
    if (i < n) {
        row_ptr[i] = ex;
        cursor[i]  = ex;
        dinv[i]    = rsqrtf(1.0f + (float)d);
        if (i == n - 1) row_ptr[n] = ex + d;
    }
}

__global__ void k_fill(const int* __restrict__ src, const int* __restrict__ dst,
                       const float* __restrict__ dinv, int* cursor,
                       int* __restrict__ csr_src, float* __restrict__ csr_w, int e) {
    int i = blockIdx.x * blockDim.x + threadIdx.x;
    if (i < e) {
        int s = src[i], d = dst[i];
        int p = atomicAdd(&cursor[d], 1);
        csr_src[p] = s;
        csr_w[p]   = dinv[s] * dinv[d];
    }
}

// ---------------- CSR gather-aggregate, float4 lanes, 4-edge unroll ----------------

template<int W, int G, bool BIAS_RELU>
__global__ void k_agg4(const float* __restrict__ T, const float* __restrict__ dinv,
                       const int* __restrict__ row_ptr, const int* __restrict__ csr_src,
                       const float* __restrict__ csr_w, const float* __restrict__ b,
                       float* __restrict__ O, int n) {
    constexpr int W4 = W / 4;
    const int gpb = 256 / G;
    int g = blockIdx.x * gpb + threadIdx.x / G;
    int j = threadIdx.x % G;
    if (g >= n || j >= W4) return;

    const float4* T4 = (const float4*)T;
    float di = dinv[g];
    float  sw = di * di;
    float4 t  = T4[(size_t)g * W4 + j];
    float4 acc = make_float4(sw * t.x, sw * t.y, sw * t.z, sw * t.w);

    int lo = row_ptr[g], hi = row_ptr[g + 1];
    int k = lo;
    // 4-deep unroll: 4 independent row-gathers in flight per lane
    for (; k + 4 <= hi; k += 4) {
        int   s0 = csr_src[k + 0], s1 = csr_src[k + 1];
        int   s2 = csr_src[k + 2], s3 = csr_src[k + 3];
        float w0 = csr_w[k + 0], w1 = csr_w[k + 1];
        float w2 = csr_w[k + 2], w3 = csr_w[k + 3];
        float4 t0 = T4[(size_t)s0 * W4 + j];
        float4 t1 = T4[(size_t)s1 * W4 + j];
        float4 t2 = T4[(size_t)s2 * W4 + j];
        float4 t3 = T4[(size_t)s3 * W4 + j];
        acc.x += w0 * t0.x; acc.y += w0 * t0.y; acc.z += w0 * t0.z; acc.w += w0 * t0.w;
        acc.x += w1 * t1.x; acc.y += w1 * t1.y; acc.z += w1 * t1.z; acc.w += w1 * t1.w;
        acc.x += w2 * t2.x; acc.y += w2 * t2.y; acc.z += w2 * t2.z; acc.w += w2 * t2.w;
        acc.x += w3 * t3.x; acc.y += w3 * t3.y; acc.z += w3 * t3.z; acc.w += w3 * t3.w;
    }
    for (; k < hi; ++k) {
        int   s = csr_src[k];
        float wc = csr_w[k];
        float4 tv = T4[(size_t)s * W4 + j];
        acc.x += wc * tv.x; acc.y += wc * tv.y;
        acc.z += wc * tv.z; acc.w += wc * tv.w;
    }
    if (BIAS_RELU) {
        float4 bv = ((const float4*)b)[j];
        acc.x = fmaxf(acc.x + bv.x, 0.0f);
        acc.y = fmaxf(acc.y + bv.y, 0.0f);
        acc.z = fmaxf(acc.z + bv.z, 0.0f);
        acc.w = fmaxf(acc.w + bv.w, 0.0f);
    }
    ((float4*)O)[(size_t)g * W4 + j] = acc;
}

// ---------------- register-blocked GEMM ----------------
// Node-tile on blockIdx.x (gridDim.x = 200, multiple of 8 so sibling
// column-blocks land on the SAME XCD: id = cy*200 + tx, id%8 = tx%8).
// Column-block on blockIdx.y.

template<int DI, int DO, int CT, bool BIAS_RELU>
__global__ void k_gemm(const float* __restrict__ X, const float* __restrict__ W,
                       const float* __restrict__ b, float* __restrict__ H, int n) {
    __shared__ float Ws[DI * CT];
    const int ct0 = blockIdx.y * CT;
    for (int i = threadIdx.x; i < DI * CT; i += blockDim.x) {
        int k = i / CT, c = i % CT;
        Ws[i] = W[k * DO + ct0 + c];
    }
    __syncthreads();

    int node = blockIdx.x * blockDim.x + threadIdx.x;
    if (node >= n) return;

    float acc[CT];
    #pragma unroll
    for (int c = 0; c < CT; ++c) acc[c] = BIAS_RELU ? b[ct0 + c] : 0.0f;

    const float4* xr = (const float4*)(X + (size_t)node * DI);
    #pragma unroll
    for (int k0 = 0; k0 < DI / 4; ++k0) {
        float4 xv = xr[k0];
        #pragma unroll
        for (int c = 0; c < CT; ++c) acc[c] += xv.x * Ws[(k0 * 4 + 0) * CT + c];
        #pragma unroll
        for (int c = 0; c < CT; ++c) acc[c] += xv.y * Ws[(k0 * 4 + 1) * CT + c];
        #pragma unroll
        for (int c = 0; c < CT; ++c) acc[c] += xv.z * Ws[(k0 * 4 + 2) * CT + c];
        #pragma unroll
        for (int c = 0; c < CT; ++c) acc[c] += xv.w * Ws[(k0 * 4 + 3) * CT + c];
    }

    float* hr = H + (size_t)node * DO + ct0;
    #pragma unroll
    for (int c4 = 0; c4 < CT / 4; ++c4) {
        float4 v;
        v.x = acc[c4 * 4 + 0]; v.y = acc[c4 * 4 + 1];
        v.z = acc[c4 * 4 + 2]; v.w = acc[c4 * 4 + 3];
        if (BIAS_RELU) {
            v.x = fmaxf(v.x, 0.0f); v.y = fmaxf(v.y, 0.0f);
            v.z = fmaxf(v.z, 0.0f); v.w = fmaxf(v.w, 0.0f);
        }
        ((float4*)hr)[c4] = v;
    }
}

// ---------------- MLP head ----------------

__global__ void k_mlp(const float* __restrict__ O3,
                      const float* __restrict__ Wf1, const float* __restrict__ bf1,
                      const float* __restrict__ Wf2, const float* __restrict__ bf2,
                      float* __restrict__ out, int n) {
    __shared__ float W1s[32 * 16];
    __shared__ float b1s[16];
    __shared__ float W2s[16];
    __shared__ float b2s;
    for (int t = threadIdx.x; t < 32 * 16; t += blockDim.x) W1s[t] = Wf1[t];
    if (threadIdx.x < 16) { b1s[threadIdx.x] = bf1[threadIdx.x]; W2s[threadIdx.x] = Wf2[threadIdx.x]; }
    if (threadIdx.x == 0) b2s = bf2[0];
    __syncthreads();

    for (int node = blockIdx.x * blockDim.x + threadIdx.x; node < n;
         node += gridDim.x * blockDim.x) {
        float h[16];
        #pragma unroll
        for (int j = 0; j < 16; ++j) h[j] = b1s[j];
        const float4* xr = (const float4*)(O3 + (size_t)node * 32);
        #pragma unroll
        for (int k4 = 0; k4 < 8; ++k4) {
            float4 xv = xr[k4];
            #pragma unroll
            for (int j = 0; j < 16; ++j) h[j] += xv.x * W1s[(k4 * 4 + 0) * 16 + j];
            #pragma unroll
            for (int j = 0; j < 16; ++j) h[j] += xv.y * W1s[(k4 * 4 + 1) * 16 + j];
            #pragma unroll
            for (int j = 0; j < 16; ++j) h[j] += xv.z * W1s[(k4 * 4 + 2) * 16 + j];
            #pragma unroll
            for (int j = 0; j < 16; ++j) h[j] += xv.w * W1s[(k4 * 4 + 3) * 16 + j];
        }
        float acc = b2s;
        #pragma unroll
        for (int j = 0; j < 16; ++j) acc += fmaxf(h[j], 0.0f) * W2s[j];
        out[node] = 1.0f / (1.0f + expf(-acc));
    }
}

// ---------------- launch ----------------

extern "C" void kernel_launch(void* const* d_in, const int* in_sizes, int n_in,
                              void* d_out, int out_size, void* d_ws, size_t ws_size,
                              hipStream_t stream) {
    const float* x   = (const float*)d_in[0];
    const int*   ei  = (const int*)d_in[1];
    const float* W1  = (const float*)d_in[2];
    const float* b1  = (const float*)d_in[3];
    const float* W2  = (const float*)d_in[4];
    const float* b2  = (const float*)d_in[5];
    const float* W3  = (const float*)d_in[6];
    const float* b3  = (const float*)d_in[7];
    const float* Wf1 = (const float*)d_in[8];
    const float* bf1 = (const float*)d_in[9];
    const float* Wf2 = (const float*)d_in[10];
    const float* bf2 = (const float*)d_in[11];
    float* out = (float*)d_out;

    const int N = N_NODES, E = N_EDGES;
    const int* src = ei;
    const int* dst = ei + E;

    char* w = (char*)d_ws;
    float* dinv    = (float*)w;                     w += (size_t)N * 4;
    int*   degc    = (int*)w;                       w += (size_t)N * 4;
    int*   row_ptr = (int*)w;                       w += (size_t)(N + 4) * 4;
    int*   cursor  = (int*)w;                       w += (size_t)N * 4;
    int*   bsum    = (int*)w;                       w += (size_t)256 * 4;
    int*   csr_src = (int*)w;                       w += (size_t)E * 4;
    float* csr_w   = (float*)w;                     w += (size_t)E * 4;
    float* bufA    = (float*)w;                     w += (size_t)N * 64 * 4;
    float* bufB    = (float*)w;                                              // N*128

    const int B   = 256;
    const int NB  = (N + B - 1) / B;        // 196
    const int NBX = 200;                    // padded to multiple of 8 (XCD count)

    // ---- CSR build ----
    k_zero     <<<NB, B, 0, stream>>>(degc, N);
    k_count    <<<(E + B - 1) / B, B, 0, stream>>>(dst, degc, E);
    k_blocksum <<<NB, B, 0, stream>>>(degc, bsum, N);
    k_scanbsum <<<1, B, 0, stream>>>(bsum, NB);
    k_rowptr   <<<NB, B, 0, stream>>>(degc, bsum, row_ptr, cursor, dinv, N);
    k_fill     <<<(E + B - 1) / B, B, 0, stream>>>(src, dst, dinv, cursor, csr_src, csr_w, E);

    // ---- layer 1: aggregate x at 44 dims, then GEMM 44->128 (+b1, relu) ----
    k_agg4<44, 16, false><<<(N * 16 + B - 1) / B, B, 0, stream>>>(
        x, dinv, row_ptr, csr_src, csr_w, nullptr, bufA, N);
    k_gemm<44, 128, 16, true><<<dim3(NBX, 8), B, 0, stream>>>(bufA, W1, b1, bufB, N);

    // ---- layer 2: GEMM 128->64, aggregate at 64 (+b2, relu) ----
    k_gemm<128, 64, 16, false><<<dim3(NBX, 4), B, 0, stream>>>(bufB, W2, nullptr, bufA, N);
    k_agg4<64, 16, true><<<(N * 16 + B - 1) / B, B, 0, stream>>>(
        bufA, dinv, row_ptr, csr_src, csr_w, b2, bufB, N);

    // ---- layer 3: GEMM 64->32, aggregate at 32 (+b3, relu) ----
    k_gemm<64, 32, 8, false><<<dim3(NBX, 4), B, 0, stream>>>(bufB, W3, nullptr, bufA, N);
    k_agg4<32, 8, true><<<(N * 8 + B - 1) / B, B, 0, stream>>>(
        bufA, dinv, row_ptr, csr_src, csr_w, b3, bufB, N);

    // ---- MLP head ----
    k_mlp<<<NB, B, 0, stream>>>(bufB, Wf1, bf1, Wf2, bf2, out, N);
}

// Round 9
// 293.996 us; speedup vs baseline: 2.4615x; 1.1218x over previous
//
#include <hip/hip_runtime.h>
#include <hip/hip_bf16.h>
#include <math.h>

#define N_NODES 50000
#define N_EDGES 600000
#define D_IN    44

// ---------------- CSR build ----------------

__global__ void k_zero(int* p, int n) {
    int i = blockIdx.x * blockDim.x + threadIdx.x;
    if (i < n) p[i] = 0;
}

__global__ void k_count(const int* __restrict__ dst, int* degc, int e) {
    int i = blockIdx.x * blockDim.x + threadIdx.x;
    if (i < e) atomicAdd(&degc[dst[i]], 1);
}

__global__ void k_blocksum(const int* __restrict__ degc, int* __restrict__ bsum, int n) {
    int i = blockIdx.x * 256 + threadIdx.x;
    int v = (i < n) ? degc[i] : 0;
    #pragma unroll
    for (int off = 32; off > 0; off >>= 1) v += __shfl_down(v, off, 64);
    __shared__ int ws[4];
    if ((threadIdx.x & 63) == 0) ws[threadIdx.x >> 6] = v;
    __syncthreads();
    if (threadIdx.x == 0) bsum[blockIdx.x] = ws[0] + ws[1] + ws[2] + ws[3];
}

__global__ void k_scanbsum(int* bsum, int nb) {
    __shared__ int s[256];
    int t = threadIdx.x;
    int v = (t < nb) ? bsum[t] : 0;
    s[t] = v;
    __syncthreads();
    #pragma unroll
    for (int off = 1; off < 256; off <<= 1) {
        int u = (t >= off) ? s[t - off] : 0;
        __syncthreads();
        s[t] += u;
        __syncthreads();
    }
    if (t < nb) bsum[t] = (t == 0) ? 0 : s[t - 1];
}

__global__ void k_rowptr(const int* __restrict__ degc, const int* __restrict__ bsum,
                         int* __restrict__ row_ptr, int* __restrict__ cursor,
                         float* __restrict__ dinv, int n) {
    __shared__ int s[256];
    int i = blockIdx.x * 256 + threadIdx.x;
    int t = threadIdx.x;
    int d = (i < n) ? degc[i] : 0;
    s[t] = d;
    __syncthreads();
    #pragma unroll
    for (int off = 1; off < 256; off <<= 1) {
        int u = (t >= off) ? s[t - off] : 0;
        __syncthreads();
        s[t] += u;
        __syncthreads();
    }
    int ex = s[t] - d + bsum[blockIdx.x];
    if (i < n) {
        row_ptr[i] = ex;
        cursor[i]  = ex;
        dinv[i]    = rsqrtf(1.0f + (float)d);
        if (i == n - 1) row_ptr[n] = ex + d;
    }
}

// interleaved CSR payload: one 8B store per edge (half the cachelines of 2x4B)
__global__ void k_fill(const int* __restrict__ src, const int* __restrict__ dst,
                       const float* __restrict__ dinv, int* cursor,
                       int2* __restrict__ csr_ew, int e) {
    int i = blockIdx.x * blockDim.x + threadIdx.x;
    if (i < e) {
        int s = src[i], d = dst[i];
        int p = atomicAdd(&cursor[d], 1);
        csr_ew[p] = make_int2(s, __float_as_int(dinv[s] * dinv[d]));
    }
}

// ---------------- CSR gather-aggregate, float4 lanes, 4-edge unroll ----------------

template<int W, int G, bool BIAS_RELU>
__global__ void k_agg4(const float* __restrict__ T, const float* __restrict__ dinv,
                       const int* __restrict__ row_ptr, const int2* __restrict__ csr_ew,
                       const float* __restrict__ b, float* __restrict__ O, int n) {
    constexpr int W4 = W / 4;
    const int gpb = 256 / G;
    int g = blockIdx.x * gpb + threadIdx.x / G;
    int j = threadIdx.x % G;
    if (g >= n || j >= W4) return;

    const float4* T4 = (const float4*)T;
    float di = dinv[g];
    float  sw = di * di;
    float4 t  = T4[(size_t)g * W4 + j];
    float4 acc = make_float4(sw * t.x, sw * t.y, sw * t.z, sw * t.w);

    int lo = row_ptr[g], hi = row_ptr[g + 1];
    int k = lo;
    for (; k + 4 <= hi; k += 4) {
        int2 e0 = csr_ew[k + 0], e1 = csr_ew[k + 1];
        int2 e2 = csr_ew[k + 2], e3 = csr_ew[k + 3];
        float w0 = __int_as_float(e0.y), w1 = __int_as_float(e1.y);
        float w2 = __int_as_float(e2.y), w3 = __int_as_float(e3.y);
        float4 t0 = T4[(size_t)e0.x * W4 + j];
        float4 t1 = T4[(size_t)e1.x * W4 + j];
        float4 t2 = T4[(size_t)e2.x * W4 + j];
        float4 t3 = T4[(size_t)e3.x * W4 + j];
        acc.x += w0 * t0.x; acc.y += w0 * t0.y; acc.z += w0 * t0.z; acc.w += w0 * t0.w;
        acc.x += w1 * t1.x; acc.y += w1 * t1.y; acc.z += w1 * t1.z; acc.w += w1 * t1.w;
        acc.x += w2 * t2.x; acc.y += w2 * t2.y; acc.z += w2 * t2.z; acc.w += w2 * t2.w;
        acc.x += w3 * t3.x; acc.y += w3 * t3.y; acc.z += w3 * t3.z; acc.w += w3 * t3.w;
    }
    for (; k < hi; ++k) {
        int2 ee = csr_ew[k];
        float wc = __int_as_float(ee.y);
        float4 tv = T4[(size_t)ee.x * W4 + j];
        acc.x += wc * tv.x; acc.y += wc * tv.y;
        acc.z += wc * tv.z; acc.w += wc * tv.w;
    }
    if (BIAS_RELU) {
        float4 bv = ((const float4*)b)[j];
        acc.x = fmaxf(acc.x + bv.x, 0.0f);
        acc.y = fmaxf(acc.y + bv.y, 0.0f);
        acc.z = fmaxf(acc.z + bv.z, 0.0f);
        acc.w = fmaxf(acc.w + bv.w, 0.0f);
    }
    ((float4*)O)[(size_t)g * W4 + j] = acc;
}

// ---------------- register-blocked GEMM (XCD-coherent swizzle) ----------------

template<int DI, int DO, int CT, bool BIAS_RELU>
__global__ void k_gemm(const float* __restrict__ X, const float* __restrict__ W,
                       const float* __restrict__ b, float* __restrict__ H, int n) {
    __shared__ float Ws[DI * CT];
    const int ct0 = blockIdx.y * CT;
    for (int i = threadIdx.x; i < DI * CT; i += blockDim.x) {
        int k = i / CT, c = i % CT;
        Ws[i] = W[k * DO + ct0 + c];
    }
    __syncthreads();

    int node = blockIdx.x * blockDim.x + threadIdx.x;
    if (node >= n) return;

    float acc[CT];
    #pragma unroll
    for (int c = 0; c < CT; ++c) acc[c] = BIAS_RELU ? b[ct0 + c] : 0.0f;

    const float4* xr = (const float4*)(X + (size_t)node * DI);
    #pragma unroll
    for (int k0 = 0; k0 < DI / 4; ++k0) {
        float4 xv = xr[k0];
        #pragma unroll
        for (int c = 0; c < CT; ++c) acc[c] += xv.x * Ws[(k0 * 4 + 0) * CT + c];
        #pragma unroll
        for (int c = 0; c < CT; ++c) acc[c] += xv.y * Ws[(k0 * 4 + 1) * CT + c];
        #pragma unroll
        for (int c = 0; c < CT; ++c) acc[c] += xv.z * Ws[(k0 * 4 + 2) * CT + c];
        #pragma unroll
        for (int c = 0; c < CT; ++c) acc[c] += xv.w * Ws[(k0 * 4 + 3) * CT + c];
    }

    float* hr = H + (size_t)node * DO + ct0;
    #pragma unroll
    for (int c4 = 0; c4 < CT / 4; ++c4) {
        float4 v;
        v.x = acc[c4 * 4 + 0]; v.y = acc[c4 * 4 + 1];
        v.z = acc[c4 * 4 + 2]; v.w = acc[c4 * 4 + 3];
        if (BIAS_RELU) {
            v.x = fmaxf(v.x, 0.0f); v.y = fmaxf(v.y, 0.0f);
            v.z = fmaxf(v.z, 0.0f); v.w = fmaxf(v.w, 0.0f);
        }
        ((float4*)hr)[c4] = v;
    }
}

// ---------------- MLP head: explicit float4 accumulators, no stride loop ----------------

__global__ void __launch_bounds__(64) k_mlp(
        const float* __restrict__ O3,
        const float* __restrict__ Wf1, const float* __restrict__ bf1,
        const float* __restrict__ Wf2, const float* __restrict__ bf2,
        float* __restrict__ out, int n) {
    __shared__ float W1s[32 * 16];
    __shared__ float b1s[16];
    __shared__ float W2s[16];
    __shared__ float b2s;
    int t = threadIdx.x;
    for (int i = t; i < 32 * 16; i += 64) W1s[i] = Wf1[i];
    if (t < 16) { b1s[t] = bf1[t]; W2s[t] = Wf2[t]; }
    if (t == 0) b2s = bf2[0];
    __syncthreads();

    int node = blockIdx.x * 64 + t;
    if (node >= n) return;

    const float4* xr = (const float4*)(O3 + (size_t)node * 32);
    float4 h0 = *(const float4*)&b1s[0];
    float4 h1 = *(const float4*)&b1s[4];
    float4 h2 = *(const float4*)&b1s[8];
    float4 h3 = *(const float4*)&b1s[12];

#define MLP_STEP(xs, krow) { \
        float4 wa = *(const float4*)&W1s[(krow) * 16 + 0];  \
        float4 wb = *(const float4*)&W1s[(krow) * 16 + 4];  \
        float4 wc = *(const float4*)&W1s[(krow) * 16 + 8];  \
        float4 wd = *(const float4*)&W1s[(krow) * 16 + 12]; \
        h0.x += (xs) * wa.x; h0.y += (xs) * wa.y; h0.z += (xs) * wa.z; h0.w += (xs) * wa.w; \
        h1.x += (xs) * wb.x; h1.y += (xs) * wb.y; h1.z += (xs) * wb.z; h1.w += (xs) * wb.w; \
        h2.x += (xs) * wc.x; h2.y += (xs) * wc.y; h2.z += (xs) * wc.z; h2.w += (xs) * wc.w; \
        h3.x += (xs) * wd.x; h3.y += (xs) * wd.y; h3.z += (xs) * wd.z; h3.w += (xs) * wd.w; }

    #pragma unroll
    for (int k4 = 0; k4 < 8; ++k4) {
        float4 xv = xr[k4];
        MLP_STEP(xv.x, k4 * 4 + 0)
        MLP_STEP(xv.y, k4 * 4 + 1)
        MLP_STEP(xv.z, k4 * 4 + 2)
        MLP_STEP(xv.w, k4 * 4 + 3)
    }
#undef MLP_STEP

    float4 va = *(const float4*)&W2s[0];
    float4 vb = *(const float4*)&W2s[4];
    float4 vc = *(const float4*)&W2s[8];
    float4 vd = *(const float4*)&W2s[12];
    float acc = b2s
        + fmaxf(h0.x, 0.0f) * va.x + fmaxf(h0.y, 0.0f) * va.y
        + fmaxf(h0.z, 0.0f) * va.z + fmaxf(h0.w, 0.0f) * va.w
        + fmaxf(h1.x, 0.0f) * vb.x + fmaxf(h1.y, 0.0f) * vb.y
        + fmaxf(h1.z, 0.0f) * vb.z + fmaxf(h1.w, 0.0f) * vb.w
        + fmaxf(h2.x, 0.0f) * vc.x + fmaxf(h2.y, 0.0f) * vc.y
        + fmaxf(h2.z, 0.0f) * vc.z + fmaxf(h2.w, 0.0f) * vc.w
        + fmaxf(h3.x, 0.0f) * vd.x + fmaxf(h3.y, 0.0f) * vd.y
        + fmaxf(h3.z, 0.0f) * vd.z + fmaxf(h3.w, 0.0f) * vd.w;
    out[node] = 1.0f / (1.0f + expf(-acc));
}

// ---------------- launch ----------------

extern "C" void kernel_launch(void* const* d_in, const int* in_sizes, int n_in,
                              void* d_out, int out_size, void* d_ws, size_t ws_size,
                              hipStream_t stream) {
    const float* x   = (const float*)d_in[0];
    const int*   ei  = (const int*)d_in[1];
    const float* W1  = (const float*)d_in[2];
    const float* b1  = (const float*)d_in[3];
    const float* W2  = (const float*)d_in[4];
    const float* b2  = (const float*)d_in[5];
    const float* W3  = (const float*)d_in[6];
    const float* b3  = (const float*)d_in[7];
    const float* Wf1 = (const float*)d_in[8];
    const float* bf1 = (const float*)d_in[9];
    const float* Wf2 = (const float*)d_in[10];
    const float* bf2 = (const float*)d_in[11];
    float* out = (float*)d_out;

    const int N = N_NODES, E = N_EDGES;
    const int* src = ei;
    const int* dst = ei + E;

    char* w = (char*)d_ws;
    float* dinv    = (float*)w;                     w += (size_t)N * 4;
    int*   degc    = (int*)w;                       w += (size_t)N * 4;
    int*   row_ptr = (int*)w;                       w += (size_t)(N + 4) * 4;
    int*   cursor  = (int*)w;                       w += (size_t)N * 4;
    int*   bsum    = (int*)w;                       w += (size_t)256 * 4;
    int2*  csr_ew  = (int2*)w;                      w += (size_t)E * 8;
    float* bufA    = (float*)w;                     w += (size_t)N * 64 * 4;
    float* bufB    = (float*)w;                                              // N*128

    const int B   = 256;
    const int NB  = (N + B - 1) / B;        // 196
    const int NBX = 200;                    // multiple of 8 (XCD count)

    // ---- CSR build ----
    k_zero     <<<NB, B, 0, stream>>>(degc, N);
    k_count    <<<(E + B - 1) / B, B, 0, stream>>>(dst, degc, E);
    k_blocksum <<<NB, B, 0, stream>>>(degc, bsum, N);
    k_scanbsum <<<1, B, 0, stream>>>(bsum, NB);
    k_rowptr   <<<NB, B, 0, stream>>>(degc, bsum, row_ptr, cursor, dinv, N);
    k_fill     <<<(E + B - 1) / B, B, 0, stream>>>(src, dst, dinv, cursor, csr_ew, E);

    // ---- layer 1: aggregate x at 44 dims, then GEMM 44->128 (+b1, relu) ----
    k_agg4<44, 16, false><<<(N * 16 + B - 1) / B, B, 0, stream>>>(
        x, dinv, row_ptr, csr_ew, nullptr, bufA, N);
    k_gemm<44, 128, 16, true><<<dim3(NBX, 8), B, 0, stream>>>(bufA, W1, b1, bufB, N);

    // ---- layer 2: GEMM 128->64, aggregate at 64 (+b2, relu) ----
    k_gemm<128, 64, 16, false><<<dim3(NBX, 4), B, 0, stream>>>(bufB, W2, nullptr, bufA, N);
    k_agg4<64, 16, true><<<(N * 16 + B - 1) / B, B, 0, stream>>>(
        bufA, dinv, row_ptr, csr_ew, b2, bufB, N);

    // ---- layer 3: GEMM 64->32, aggregate at 32 (+b3, relu) ----
    k_gemm<64, 32, 8, false><<<dim3(NBX, 4), B, 0, stream>>>(bufB, W3, nullptr, bufA, N);
    k_agg4<32, 8, true><<<(N * 8 + B - 1) / B, B, 0, stream>>>(
        bufA, dinv, row_ptr, csr_ew, b3, bufB, N);

    // ---- MLP head ----
    k_mlp<<<(N + 63) / 64, 64, 0, stream>>>(bufB, Wf1, bf1, Wf2, bf2, out, N);
}